// Round 4
// baseline (3131.469 us; speedup 1.0000x reference)
//
#include <hip/hip_runtime.h>
#include <cstdint>

typedef unsigned short u16;
typedef unsigned int   u32;

#define D_MODEL 4096
#define HIDDEN  16384
#define NTOK    4096

typedef short bf16x8  __attribute__((ext_vector_type(8)));
typedef float floatx4 __attribute__((ext_vector_type(4)));

typedef __attribute__((address_space(1))) u32 gu32;
typedef __attribute__((address_space(3))) u32 lu32;

__device__ __forceinline__ void gl_lds16(const void* g, void* l) {
  __builtin_amdgcn_global_load_lds((gu32*)g, (lu32*)l, 16, 0, 0);
}

__device__ __forceinline__ u16 f32_bf16_rne(float f) {
  union { float f; u32 u; } c; c.f = f;
  u32 u = c.u;
  return (u16)((u + 0x7FFFu + ((u >> 16) & 1u)) >> 16);
}

__device__ __forceinline__ u32 cvt_pk_bf16(float lo, float hi) {
  u32 r;
  asm("v_cvt_pk_bf16_f32 %0, %1, %2" : "=v"(r) : "v"(lo), "v"(hi));
  return r;
}

__device__ __forceinline__ float gelu_tanh(float x) {
  // jax.nn.gelu approximate=True; tanh via v_exp, overflow-safe form
  float inner = 0.7978845608028654f * fmaf(0.044715f * x * x, x, x);
  float e  = __expf(2.0f * inner);
  float th = 1.0f - 2.0f / (e + 1.0f);
  return 0.5f * x * (1.0f + th);
}

// x fp32 -> bf16, 4-wide.
__global__ void __launch_bounds__(256) cvt_f32_bf16(const float4* __restrict__ in,
                                                    ushort4* __restrict__ out) {
  int i = blockIdx.x * 256 + threadIdx.x;
  float4 v = in[i];
  ushort4 o;
  o.x = f32_bf16_rne(v.x);
  o.y = f32_bf16_rne(v.y);
  o.z = f32_bf16_rne(v.z);
  o.w = f32_bf16_rne(v.w);
  out[i] = o;
}

// Repack int32-per-byte (values 0..255) -> true nibble bytes. Thread: 16 int32 -> 16 B.
__global__ void __launch_bounds__(256)
repack_nib(const int4* __restrict__ in, uint4* __restrict__ out) {
  const size_t i = (size_t)blockIdx.x * 256 + threadIdx.x;
  int4 a = in[4 * i + 0], b = in[4 * i + 1], c = in[4 * i + 2], d = in[4 * i + 3];
  uint4 o;
  o.x = (u32)(a.x & 255) | ((u32)(a.y & 255) << 8) | ((u32)(a.z & 255) << 16) | ((u32)(a.w & 255) << 24);
  o.y = (u32)(b.x & 255) | ((u32)(b.y & 255) << 8) | ((u32)(b.z & 255) << 16) | ((u32)(b.w & 255) << 24);
  o.z = (u32)(c.x & 255) | ((u32)(c.y & 255) << 8) | ((u32)(c.z & 255) << 16) | ((u32)(c.w & 255) << 24);
  o.w = (u32)(d.x & 255) | ((u32)(d.y & 255) << 8) | ((u32)(d.z & 255) << 16) | ((u32)(d.w & 255) << 24);
  out[i] = o;
}

// Dequant one packed dword (4 nibble-bytes = 8 weights, hi nibble = even col) to
// 8 bf16 and store 16 B to LDS.
__device__ __forceinline__ void wr8(char* d, u32 v, float s, float m8s) {
  u32 b0 = v & 0xFFu, b1 = (v >> 8) & 0xFFu, b2 = (v >> 16) & 0xFFu, b3 = v >> 24;
  uint4 q;
  q.x = cvt_pk_bf16(fmaf((float)(b0 >> 4), s, m8s), fmaf((float)(b0 & 15u), s, m8s));
  q.y = cvt_pk_bf16(fmaf((float)(b1 >> 4), s, m8s), fmaf((float)(b1 & 15u), s, m8s));
  q.z = cvt_pk_bf16(fmaf((float)(b2 >> 4), s, m8s), fmaf((float)(b2 & 15u), s, m8s));
  q.w = cvt_pk_bf16(fmaf((float)(b3 >> 4), s, m8s), fmaf((float)(b3 & 15u), s, m8s));
  *(uint4*)d = q;
}

// ---------------------------------------------------------------------------
// 128(M)x256(N) / BK=32, 1-phase-per-tile NT-GEMM, 2 blocks/CU (TLP fix).
// C[M,N] = A[M,K] * (scale * W4)[rows,K]^T.
// 512 threads = 8 waves (2M x 4N), per-wave 64x64 out, acc[4][4] (64 VGPR).
// LDS 64 KiB: A quad-buffer 4 x 8 KiB (seg [128][32] bf16) @ 0,
//             B double-buffer 2 x 16 KiB (seg [256][32] bf16) @ 32768.
// st_16x32 swizzle (byte^=((byte>>9)&1)<<5) via pre-swizzled source columns,
// linear LDS placement (gl_lds / ds_write), swizzled ds_read — as verified in
// the round-2/3 kernels.
//
// Per phase u: ds_read af[4](Ab[u&3]) + bf[4](Bb[u&1]); ASTG A(u+2)->Ab[(u+2)&3]
// (2-phase lead); BLOAD nib(u+3) regs; BDEQ B(u+1)->Bb[(u+1)&1] (regs loaded
// 2 phases ago, LDS-write lead 1 phase = lgkm+barrier covered); barrier;
// lgkmcnt(0); 16 MFMA; vmcnt(5); barrier.
// vmcnt rank-count (per-phase issues in order [a, b, b]): at end of phase v the
// queue is [a(v-1),bb(v-1),a(v),bb(v)] (6); vmcnt(5) completes a(v-1) = the
// A-seg consumed at phase v+1. Tail: vmcnt 5/3/0 as staging drops off.
// Targets are stage-after-death: Ab[(u+2)&3] died phase u-2; Bb[(u+1)&1] died
// phase u-1 (one barrier ago minimum).
// ---------------------------------------------------------------------------

#define VMW(N) asm volatile("s_waitcnt vmcnt(" #N ")" ::: "memory")
#define FEN()  asm volatile("" ::: "memory")

#define ASTG(T) gl_lds16(ast0 + (size_t)(T) * 32, ldsw + (((T) & 3) << 13) + (wave << 10))

#define BLOAD(T, Q)                                                            \
  do {                                                                         \
    Q.x = bn0[(T) * 4];                                                        \
    Q.y = bn1[(T) * 4];                                                        \
  } while (0)

#define BDEQ(T, Q)                                                             \
  do {                                                                         \
    char* d_ = ldsw + 32768 + (((T) & 1) << 14) + (w2 << 10) + lane * 16;      \
    wr8(d_, (Q).x, s0, m8s0);                                                  \
    wr8(d_ + 1024, (Q).y, s1, m8s1);                                           \
  } while (0)

#define PH(AB, BB, VME, STG)                                                   \
  do {                                                                         \
    _Pragma("unroll")                                                          \
    for (int f_ = 0; f_ < 4; ++f_)                                             \
      af[f_] = *(const bf16x8*)(ldsr + ((AB) << 13) + f_ * 1024 + aoff);       \
    _Pragma("unroll")                                                          \
    for (int f_ = 0; f_ < 4; ++f_)                                             \
      bf[f_] = *(const bf16x8*)(ldsr + 32768 + ((BB) << 14) + f_ * 1024 + boff);\
    STG;                                                                       \
    __builtin_amdgcn_s_barrier();                                              \
    asm volatile("s_waitcnt lgkmcnt(0)" ::: "memory");                         \
    __builtin_amdgcn_sched_barrier(0);                                         \
    __builtin_amdgcn_s_setprio(1);                                             \
    _Pragma("unroll")                                                          \
    for (int f_ = 0; f_ < 4; ++f_) {                                           \
      _Pragma("unroll")                                                        \
      for (int n_ = 0; n_ < 4; ++n_)                                           \
        acc[f_][n_] = __builtin_amdgcn_mfma_f32_16x16x32_bf16(                 \
            af[f_], bf[n_], acc[f_][n_], 0, 0, 0);                             \
    }                                                                          \
    __builtin_amdgcn_s_setprio(0);                                             \
    if ((VME) == 5) VMW(5);                                                    \
    if ((VME) == 3) VMW(3);                                                    \
    if ((VME) == 0) VMW(0);                                                    \
    __builtin_amdgcn_s_barrier();                                              \
  } while (0)

template <int K, int N, bool GELU>
__global__ void __launch_bounds__(512, 4)
gemm_f(const u16* __restrict__ A, const u32* __restrict__ Bnib,
       const float* __restrict__ Bsc, u16* __restrict__ Cb,
       float* __restrict__ Cf) {
  __shared__ __align__(16) u16 lds[32768];   // 64 KiB
  char* ldsw = (char*)lds;
  const char* ldsr = (const char*)lds;

  const int tid  = threadIdx.x;
  const int lane = tid & 63;
  const int wave = tid >> 6;       // 0..7
  const int quad = lane >> 4;
  const int l16  = lane & 15;
  const int wm   = wave >> 2;      // 0..1  (M half, 64 rows)
  const int wn   = wave & 3;       // 0..3  (N quarter, 64 cols)

  // bijective XCD-aware block swizzle (m204)
  const int gx  = gridDim.x;
  const int nwg = gx * gridDim.y;
  const int orig = blockIdx.y * gx + blockIdx.x;
  const int q = nwg >> 3, r = nwg & 7;
  const int xcd = orig & 7, lid = orig >> 3;
  const int wgid = (xcd < r ? xcd * (q + 1) : r * (q + 1) + (xcd - r) * q) + lid;
  const int n0 = (wgid % gx) * 256;
  const int m0 = (wgid / gx) * 128;

  // A staging: 1 gl_lds/thread/seg. Linear dest byte o = wave*1024 + lane*16;
  // pre-swizzled source: row = wave*16 + lane/4, kcol = (lane&3)*8 ^ (lane>=32?16:0).
  const int w2   = wave * 2;
  const int rl   = lane >> 2;
  const int kcol = ((lane & 3) * 8) ^ ((lane & 32) ? 16 : 0);
  const u16* ast0 = A + (size_t)(m0 + wave * 16 + rl) * K + kcol;

  // B nibble pointers (same pre-swizzled columns): row stride K/8 dwords.
  const int brow0 = n0 + w2 * 16 + rl;
  const u32* bn0 = Bnib + (size_t)brow0 * (K / 8) + (kcol >> 3);
  const u32* bn1 = Bnib + (size_t)(brow0 + 16) * (K / 8) + (kcol >> 3);
  const float s0 = Bsc[brow0];
  const float s1 = Bsc[brow0 + 16];
  const float m8s0 = -8.0f * s0;
  const float m8s1 = -8.0f * s1;

  // Swizzled ds_read byte offsets (frag f adds f*1024; wm*4096 / wn*4096 are
  // bits>=12, so they commute with the bit-5 XOR keyed on bit 9).
  u32 pa = (u32)((wm * 64 + l16) * 64 + quad * 16);
  const u32 aoff = pa ^ (((pa >> 9) & 1) << 5);
  u32 pb = (u32)((wn * 64 + l16) * 64 + quad * 16);
  const u32 boff = pb ^ (((pb >> 9) & 1) << 5);

  floatx4 acc[4][4];
#pragma unroll
  for (int i = 0; i < 4; ++i)
#pragma unroll
    for (int j = 0; j < 4; ++j) acc[i][j] = (floatx4){0.f, 0.f, 0.f, 0.f};

  bf16x8 af[4], bf[4];
  uint2 q0, q1, q2, q3;

  // Prologue: A(0)->Ab0, A(1)->Ab1; nib(0..2) to q0..q2; B(0) dequant.
  ASTG(0); ASTG(1);
  BLOAD(0, q0); BLOAD(1, q1); BLOAD(2, q2);
  FEN();
  VMW(6);                        // forces the two A gl_lds (oldest in queue)
  BDEQ(0, q0);                   // compiler scoreboards q0 regs
  asm volatile("s_waitcnt lgkmcnt(0)" ::: "memory");
  __builtin_amdgcn_s_barrier();

  const int KT = K / 32;         // multiple of 4
  // Steady: phase j of 4: BDEQ B(u+j+1) from q[(j+1)&3]; BLOAD nib(u+j+3) to q[(j+3)&3].
  for (int u = 0; u < KT - 4; u += 4) {
    PH(0, 0, 5, BDEQ(u + 1, q1); ASTG(u + 2); BLOAD(u + 3, q3); FEN());
    PH(1, 1, 5, BDEQ(u + 2, q2); ASTG(u + 3); BLOAD(u + 4, q0); FEN());
    PH(2, 0, 5, BDEQ(u + 3, q3); ASTG(u + 4); BLOAD(u + 5, q1); FEN());
    PH(3, 1, 5, BDEQ(u + 4, q0); ASTG(u + 5); BLOAD(u + 6, q2); FEN());
  }
  {
    const int u = KT - 4;        // phases KT-4 .. KT-1 (AB = u&3 = 0..3 since KT%4==0)
    PH(0, 0, 5, BDEQ(u + 1, q1); ASTG(u + 2); BLOAD(u + 3, q3); FEN());
    PH(1, 1, 3, BDEQ(u + 2, q2); ASTG(u + 3); FEN());
    PH(2, 0, 0, BDEQ(u + 3, q3));
    PH(3, 1, -1, (void)0);
  }

  // Epilogue. C/D layout: col = lane&15, row = quad*4 + reg (m89/m91 verified).
  const int crow0 = m0 + wm * 64 + quad * 4;
  const int ccol0 = n0 + wn * 64 + l16;
#pragma unroll
  for (int mf = 0; mf < 4; ++mf) {
#pragma unroll
    for (int rr = 0; rr < 4; ++rr) {
      const size_t row = (size_t)(crow0 + mf * 16 + rr);
#pragma unroll
      for (int nf = 0; nf < 4; ++nf) {
        float v = acc[mf][nf][rr];
        const size_t idx = row * N + (size_t)(ccol0 + nf * 16);
        if constexpr (GELU) {
          Cb[idx] = f32_bf16_rne(gelu_tanh(v));
        } else {
          Cf[idx] = v;
        }
      }
    }
  }
}

#undef PH
#undef BDEQ
#undef BLOAD
#undef ASTG
#undef VMW
#undef FEN

// ---------------- Fallback: fused dequant GEMM (ws too small) ------------
template <int K, int N, bool GELU>
__global__ void __launch_bounds__(256)
gemm_dq(const u16* __restrict__ A, const int* __restrict__ Bp,
        const float* __restrict__ Bsc, u16* __restrict__ Cb, float* __restrict__ Cf) {
  __shared__ __align__(16) u16 As[128 * 32];
  __shared__ __align__(16) u16 Bs[128 * 32];

  const int tid  = threadIdx.x;
  const int lane = tid & 63;
  const int wave = tid >> 6;
  const int quad = lane >> 4;
  const int l16  = lane & 15;
  const int wm = wave >> 1, wn = wave & 1;

  const int n0 = blockIdx.x * 128;
  const int m0 = blockIdx.y * 128;

  const int brow  = tid >> 1;
  const int bhalf = tid & 1;
  const float s   = Bsc[n0 + brow];
  const float m8s = -8.0f * s;
  const int4* bp  = (const int4*)(Bp + (size_t)(n0 + brow) * (K / 2)) + bhalf * 2;
  u16* blds = Bs + (brow >> 4) * 512 + (2 * bhalf) * 128 + (brow & 15) * 8;

  const u16* ag = A + (size_t)(m0 + l16) * K + (size_t)quad * 8;
  u16* alds0 = As + (wave * 2 + 0) * 512;
  u16* alds1 = As + (wave * 2 + 1) * 512;

  floatx4 acc[4][4];
#pragma unroll
  for (int i = 0; i < 4; ++i)
#pragma unroll
    for (int j = 0; j < 4; ++j)
      acc[i][j] = (floatx4){0.f, 0.f, 0.f, 0.f};

  const int KT = K / 32;
  for (int kt = 0; kt < KT; ++kt) {
    int4 w0 = bp[(size_t)kt * 4 + 0];
    int4 w1 = bp[(size_t)kt * 4 + 1];
    __syncthreads();
    gl_lds16(ag + (size_t)(wave * 2 + 0) * 16 * K + kt * 32, alds0);
    gl_lds16(ag + (size_t)(wave * 2 + 1) * 16 * K + kt * 32, alds1);
    int wv[8] = {w0.x, w0.y, w0.z, w0.w, w1.x, w1.y, w1.z, w1.w};
    union { u16 e[16]; uint4 q[2]; } u;
#pragma unroll
    for (int j = 0; j < 8; ++j) {
      int v = wv[j];
      u.e[2 * j]     = f32_bf16_rne(fmaf((float)(v >> 4), s, m8s));
      u.e[2 * j + 1] = f32_bf16_rne(fmaf((float)(v & 15), s, m8s));
    }
    *(uint4*)(blds)       = u.q[0];
    *(uint4*)(blds + 128) = u.q[1];
    __syncthreads();

    bf16x8 af[4], bf[4];
#pragma unroll
    for (int im = 0; im < 4; ++im)
      af[im] = *(const bf16x8*)(As + (wm * 4 + im) * 512 + quad * 128 + l16 * 8);
#pragma unroll
    for (int in = 0; in < 4; ++in)
      bf[in] = *(const bf16x8*)(Bs + (wn * 4 + in) * 512 + quad * 128 + l16 * 8);
#pragma unroll
    for (int im = 0; im < 4; ++im)
#pragma unroll
      for (int in = 0; in < 4; ++in)
        acc[im][in] = __builtin_amdgcn_mfma_f32_16x16x32_bf16(af[im], bf[in], acc[im][in], 0, 0, 0);
  }

#pragma unroll
  for (int im = 0; im < 4; ++im) {
#pragma unroll
    for (int r = 0; r < 4; ++r) {
      const int row = m0 + wm * 64 + im * 16 + quad * 4 + r;
#pragma unroll
      for (int in = 0; in < 4; ++in) {
        const int col = n0 + wn * 64 + in * 16 + l16;
        float v = acc[im][in][r];
        if constexpr (GELU) {
          Cb[(size_t)row * N + col] = f32_bf16_rne(gelu_tanh(v));
        } else {
          Cf[(size_t)row * N + col] = v;
        }
      }
    }
  }
}

extern "C" void kernel_launch(void* const* d_in, const int* in_sizes, int n_in,
                              void* d_out, int out_size, void* d_ws, size_t ws_size,
                              hipStream_t stream) {
  const float* x   = (const float*)d_in[0];
  const int*   f1p = (const int*)d_in[1];
  const float* f1s = (const float*)d_in[2];
  const int*   f2p = (const int*)d_in[3];
  const float* f2s = (const float*)d_in[4];
  float* out = (float*)d_out;

  const size_t xb_bytes  = (size_t)NTOK * D_MODEL * 2;            // 32 MiB
  const size_t h_bytes   = (size_t)NTOK * HIDDEN * 2;             // 128 MiB
  const size_t nib_bytes = (size_t)HIDDEN * D_MODEL / 2;          // 32 MiB each
  const size_t base      = xb_bytes + h_bytes;
  if (ws_size < base) return;

  u16* xb = (u16*)d_ws;
  u16* h  = xb + (size_t)NTOK * D_MODEL;

  cvt_f32_bf16<<<(NTOK * D_MODEL) / 1024, 256, 0, stream>>>((const float4*)x, (ushort4*)xb);

  if (ws_size < base + 2 * nib_bytes) {
    // Fallback: fused dequant path (needs no extra ws)
    gemm_dq<D_MODEL, HIDDEN, true>
        <<<dim3(HIDDEN / 128, NTOK / 128), 256, 0, stream>>>(xb, f1p, f1s, h, nullptr);
    gemm_dq<HIDDEN, D_MODEL, false>
        <<<dim3(D_MODEL / 128, NTOK / 128), 256, 0, stream>>>(h, f2p, f2s, nullptr, out);
    return;
  }

  u32* nib1 = (u32*)(h + (size_t)NTOK * HIDDEN);                  // 32 MiB
  u32* nib2 = nib1 + nib_bytes / 4;                               // 32 MiB

  // Repack int32-per-byte packed weights to true nibble buffers.
  const int nblk = (int)((size_t)HIDDEN * (D_MODEL / 2) / 16 / 256);  // 8192
  repack_nib<<<nblk, 256, 0, stream>>>((const int4*)f1p, (uint4*)nib1);
  repack_nib<<<nblk, 256, 0, stream>>>((const int4*)f2p, (uint4*)nib2);

  // GEMM1: h = gelu(x @ W1^T)
  gemm_f<D_MODEL, HIDDEN, true>
      <<<dim3(HIDDEN / 256, NTOK / 128), 512, 0, stream>>>(xb, nib1, f1s, h, nullptr);
  // GEMM2: out = h @ W2^T
  gemm_f<HIDDEN, D_MODEL, false>
      <<<dim3(D_MODEL / 256, NTOK / 128), 512, 0, stream>>>(h, nib2, f2s, nullptr, out);
}

// Round 5
// 1279.564 us; speedup vs baseline: 2.4473x; 2.4473x over previous
//
#include <hip/hip_runtime.h>
#include <cstdint>

typedef unsigned short u16;
typedef unsigned int   u32;

#define D_MODEL 4096
#define HIDDEN  16384
#define NTOK    4096

typedef _Float16 f16x8 __attribute__((ext_vector_type(8)));
typedef _Float16 h2    __attribute__((ext_vector_type(2)));
typedef float floatx4  __attribute__((ext_vector_type(4)));

typedef __attribute__((address_space(1))) u32 gu32;
typedef __attribute__((address_space(3))) u32 lu32;

__device__ __forceinline__ void gl_lds16(const void* g, void* l) {
  __builtin_amdgcn_global_load_lds((gu32*)g, (lu32*)l, 16, 0, 0);
}

__device__ __forceinline__ u16 f32_f16(float f) {
  _Float16 h = (_Float16)f;   // v_cvt_f16_f32, RNE
  return __builtin_bit_cast(u16, h);
}

__device__ __forceinline__ float gelu_tanh(float x) {
  // jax.nn.gelu approximate=True; tanh via v_exp, overflow-safe form
  float inner = 0.7978845608028654f * fmaf(0.044715f * x * x, x, x);
  float e  = __expf(2.0f * inner);
  float th = 1.0f - 2.0f / (e + 1.0f);
  return 0.5f * x * (1.0f + th);
}

// x fp32 -> f16, 4-wide.
__global__ void __launch_bounds__(256) cvt_f32_f16(const float4* __restrict__ in,
                                                   ushort4* __restrict__ out) {
  int i = blockIdx.x * 256 + threadIdx.x;
  float4 v = in[i];
  ushort4 o;
  o.x = f32_f16(v.x);
  o.y = f32_f16(v.y);
  o.z = f32_f16(v.z);
  o.w = f32_f16(v.w);
  out[i] = o;
}

// Repack int32-per-byte (values 0..255) -> true nibble bytes. Thread: 16 int32 -> 16 B.
__global__ void __launch_bounds__(256)
repack_nib(const int4* __restrict__ in, uint4* __restrict__ out) {
  const size_t i = (size_t)blockIdx.x * 256 + threadIdx.x;
  int4 a = in[4 * i + 0], b = in[4 * i + 1], c = in[4 * i + 2], d = in[4 * i + 3];
  uint4 o;
  o.x = (u32)(a.x & 255) | ((u32)(a.y & 255) << 8) | ((u32)(a.z & 255) << 16) | ((u32)(a.w & 255) << 24);
  o.y = (u32)(b.x & 255) | ((u32)(b.y & 255) << 8) | ((u32)(b.z & 255) << 16) | ((u32)(b.w & 255) << 24);
  o.z = (u32)(c.x & 255) | ((u32)(c.y & 255) << 8) | ((u32)(c.z & 255) << 16) | ((u32)(c.w & 255) << 24);
  o.w = (u32)(d.x & 255) | ((u32)(d.y & 255) << 8) | ((u32)(d.z & 255) << 16) | ((u32)(d.w & 255) << 24);
  out[i] = o;
}

// Dequant one packed dword (4 nibble-bytes = 8 weights, hi nibble = even col) to
// 8 UNSCALED f16 integers (n-8) and store 16 B to LDS. ~15 VALU:
// f16 magic: (0x6400|n) = 1024+n exactly; v_pk_add_f16(-1032) -> n-8 exactly;
// v_perm_b32 restores memory order [hi0,lo0,hi1,lo1,hi2,lo2,hi3,lo3].
// Row scale is applied in the GEMM epilogue (factors out of the K-sum).
__device__ __forceinline__ void wr8i(char* d, u32 v) {
  const u32 M = 0x000F000Fu, G = 0x64006400u;
  const h2 C = __builtin_bit_cast(h2, 0xE408E408u);   // {-1032h, -1032h}
  u32 d0 = __builtin_bit_cast(u32, __builtin_bit_cast(h2, ((v >> 4) & M) | G) + C);  // (hi0,hi2)
  u32 d1 = __builtin_bit_cast(u32, __builtin_bit_cast(h2, (v & M) | G) + C);         // (lo0,lo2)
  u32 d2 = __builtin_bit_cast(u32, __builtin_bit_cast(h2, ((v >> 12) & M) | G) + C); // (hi1,hi3)
  u32 d3 = __builtin_bit_cast(u32, __builtin_bit_cast(h2, ((v >> 8) & M) | G) + C);  // (lo1,lo3)
  uint4 q;
  q.x = __builtin_amdgcn_perm(d1, d0, 0x05040100u);   // (hi0,lo0)
  q.y = __builtin_amdgcn_perm(d3, d2, 0x05040100u);   // (hi1,lo1)
  q.z = __builtin_amdgcn_perm(d1, d0, 0x07060302u);   // (hi2,lo2)
  q.w = __builtin_amdgcn_perm(d3, d2, 0x07060302u);   // (hi3,lo3)
  *(uint4*)d = q;
}

// ---------------------------------------------------------------------------
// 256x256 / BK=64 8-phase pipelined NT-GEMM, fused nibble-dequant B (f16 path).
// Structure identical to the verified round-3 kernel (1 block/CU, no spill);
// changes: (1) BDEQ moved from the pre-barrier slot to POST-MFMA (off the
// pre-MFMA lgkmcnt(0) critical path; own lgkmcnt(0) drain before end barrier —
// consumer reads are >=1 barrier later, stage-after-death unchanged);
// (2) dequant = packed-f16 integer trick (15 VALU / 8 weights, exact), scale
// applied per-column in the epilogue. vmcnt schedule identical to round 3.
// ---------------------------------------------------------------------------

#define VMW(N) asm volatile("s_waitcnt vmcnt(" #N ")" ::: "memory")
#define LGK0() asm volatile("s_waitcnt lgkmcnt(0)" ::: "memory")
#define FEN()  asm volatile("" ::: "memory")

#define ASTG(T, SEG)                                                           \
  do {                                                                         \
    const size_t kof_ = (size_t)(T) * 64 + (size_t)(((SEG) >> 1) * 32);        \
    char* d_ = ldsw + (((T) & 1) << 16) + ((SEG) << 14) + (w2 << 10);          \
    gl_lds16(ast0 + kof_, d_);                                                 \
    gl_lds16(ast1 + kof_, d_ + 1024);                                          \
  } while (0)

#define BLOAD(T, DST)                                                          \
  do {                                                                         \
    DST.x = bn0[(T) * 8];                                                      \
    DST.y = bn0[(T) * 8 + 4];                                                  \
    DST.z = bn1[(T) * 8];                                                      \
    DST.w = bn1[(T) * 8 + 4];                                                  \
  } while (0)

#define BDEQ(T, KS, V0, V1)                                                    \
  do {                                                                         \
    char* d_ = ldsw + (((T) & 1) << 16) + ((1 + 2 * (KS)) << 14) +             \
               (w2 << 10) + lane * 16;                                         \
    wr8i(d_, (V0));                                                            \
    wr8i(d_ + 1024, (V1));                                                     \
  } while (0)

#define PH(BB, MH, S, RDB, PRE, POST)                                          \
  do {                                                                         \
    const char* ab_ = ldsr + ((BB) << 16) + ((S) * 32768);                     \
    _Pragma("unroll")                                                          \
    for (int f_ = 0; f_ < 4; ++f_)                                             \
      af[f_] = *(const f16x8*)(ab_ + ((MH) * 4 + f_) * 1024 + aoff);           \
    if (RDB) {                                                                 \
      _Pragma("unroll")                                                        \
      for (int f_ = 0; f_ < 4; ++f_)                                           \
        bf[f_] = *(const f16x8*)(ab_ + 16384 + f_ * 1024 + boff);              \
    }                                                                          \
    PRE;                                                                       \
    __builtin_amdgcn_s_barrier();                                              \
    LGK0();                                                                    \
    __builtin_amdgcn_sched_barrier(0);                                         \
    __builtin_amdgcn_s_setprio(1);                                             \
    _Pragma("unroll")                                                          \
    for (int f_ = 0; f_ < 4; ++f_) {                                           \
      _Pragma("unroll")                                                        \
      for (int n_ = 0; n_ < 4; ++n_)                                           \
        acc[(MH) * 4 + f_][n_] = __builtin_amdgcn_mfma_f32_16x16x32_f16(       \
            af[f_], bf[n_], acc[(MH) * 4 + f_][n_], 0, 0, 0);                  \
    }                                                                          \
    __builtin_amdgcn_s_setprio(0);                                             \
    POST;                                                                      \
    __builtin_amdgcn_s_barrier();                                              \
  } while (0)

template <int K, int N, bool GELU>
__global__ void __launch_bounds__(512, 2)
gemm_nt8(const u16* __restrict__ A, const u32* __restrict__ Bnib,
         const float* __restrict__ Bsc, u16* __restrict__ Cb,
         float* __restrict__ Cf) {
  __shared__ __align__(16) u16 lds[2 * 4 * 8192];   // 128 KiB
  char* ldsw = (char*)lds;
  const char* ldsr = (const char*)lds;

  const int tid  = threadIdx.x;
  const int lane = tid & 63;
  const int wave = tid >> 6;       // 0..7
  const int quad = lane >> 4;
  const int l16  = lane & 15;
  const int wm   = wave >> 2;      // 0..1
  const int wn   = wave & 3;       // 0..3

  // bijective XCD-aware block swizzle (m204)
  const int gx  = gridDim.x;
  const int nwg = gx * gridDim.y;
  const int orig = blockIdx.y * gx + blockIdx.x;
  const int q = nwg >> 3, r = nwg & 7;
  const int xcd = orig & 7, lid = orig >> 3;
  const int wgid = (xcd < r ? xcd * (q + 1) : r * (q + 1) + (xcd - r) * q) + lid;
  const int n0 = (wgid % gx) * 256;
  const int m0 = (wgid / gx) * 256;

  // Epilogue column scales (issued FIRST so they are the oldest vm ops and get
  // forced out by the prologue VMW(8); consumed only in the epilogue).
  float scl[4];
#pragma unroll
  for (int nf = 0; nf < 4; ++nf) scl[nf] = Bsc[n0 + wn * 64 + nf * 16 + l16];
  FEN();

  // A staging: thread covers the two 1KB chunks W = wave*2, wave*2+1 of each seg.
  // Linear dest byte o = W*1024 + lane*16; pre-swizzled source:
  // row = W*16 + lane/4, kcol (u16) = (lane&3)*8 ^ (lane>=32 ? 16 : 0).
  const int w2   = wave * 2;
  const int rl   = lane >> 2;
  const int kcol = ((lane & 3) * 8) ^ ((lane & 32) ? 16 : 0);
  const u16* ast0 = A + (size_t)(m0 + w2 * 16 + rl) * K + kcol;
  const u16* ast1 = ast0 + (size_t)16 * K;

  // B nibble pointers (same pre-swizzled columns): row stride K/8 u32.
  const int brow0 = n0 + w2 * 16 + rl;
  const u32* bn0 = Bnib + (size_t)brow0 * (K / 8) + (kcol >> 3);
  const u32* bn1 = Bnib + (size_t)(brow0 + 16) * (K / 8) + (kcol >> 3);

  // Swizzled ds_read byte offsets.
  u32 pa = (u32)((wm * 128 + l16) * 64 + quad * 16);
  const u32 aoff = pa ^ (((pa >> 9) & 1) << 5);
  u32 pb = (u32)((wn * 64 + l16) * 64 + quad * 16);
  const u32 boff = pb ^ (((pb >> 9) & 1) << 5);

  floatx4 acc[8][4];
#pragma unroll
  for (int i = 0; i < 8; ++i)
#pragma unroll
    for (int j = 0; j < 4; ++j) acc[i][j] = (floatx4){0.f, 0.f, 0.f, 0.f};

  f16x8 af[4], bf[4];
  uint4 bt0, bt1, bq0, bq1, bq0n, bq1n;

  // Prologue: A: buf0.Ak0(0), buf0.Ak1(0), buf1.Ak0(1); B: tiles 0..3 to regs.
  ASTG(0, 0); ASTG(0, 2); ASTG(1, 0);
  BLOAD(0, bt0); BLOAD(1, bt1); BLOAD(2, bq0); BLOAD(3, bq1);
  FEN();
  VMW(8);   // forces scl + A gl_lds + bt0/bt1; bq0/bq1 may remain in flight
  BDEQ(0, 0, bt0.x, bt0.z);
  BDEQ(0, 1, bt0.y, bt0.w);
  BDEQ(1, 0, bt1.x, bt1.z);
  BDEQ(1, 1, bt1.y, bt1.w);
  LGK0();
  __builtin_amdgcn_s_barrier();

  const int KT = K / 64;
  for (int t = 0; t < KT - 4; t += 2) {
    // tile t (buf 0)
    PH(0, 0, 0, 1, ASTG(t + 1, 2); BLOAD(t + 4, bq0n); FEN(), (void)0);
    PH(0, 1, 0, 0, (void)0,        VMW(8); BDEQ(t + 2, 0, bq0.x, bq0.z); LGK0());
    PH(0, 1, 1, 1, ASTG(t + 2, 0); FEN(), (void)0);
    PH(0, 0, 1, 0, (void)0,        VMW(8); BDEQ(t + 2, 1, bq0.y, bq0.w); LGK0());
    // tile t+1 (buf 1)
    PH(1, 0, 0, 1, ASTG(t + 2, 2); BLOAD(t + 5, bq1n); FEN(), (void)0);
    PH(1, 1, 0, 0, (void)0,        VMW(8); BDEQ(t + 3, 0, bq1.x, bq1.z); LGK0());
    PH(1, 1, 1, 1, ASTG(t + 3, 0); FEN(), (void)0);
    PH(1, 0, 1, 0, (void)0,        VMW(8); BDEQ(t + 3, 1, bq1.y, bq1.w); LGK0());
    bq0 = bq0n;
    bq1 = bq1n;
  }
  {
    const int t = KT - 4;   // epilogue A: no more B loads
    PH(0, 0, 0, 1, ASTG(t + 1, 2); FEN(), (void)0);
    PH(0, 1, 0, 0, (void)0, VMW(8); BDEQ(t + 2, 0, bq0.x, bq0.z); LGK0());
    PH(0, 1, 1, 1, ASTG(t + 2, 0); FEN(), (void)0);
    PH(0, 0, 1, 0, (void)0, VMW(4); BDEQ(t + 2, 1, bq0.y, bq0.w); LGK0());
    PH(1, 0, 0, 1, ASTG(t + 2, 2); FEN(), (void)0);
    PH(1, 1, 0, 0, (void)0, VMW(4); BDEQ(t + 3, 0, bq1.x, bq1.z); LGK0());
    PH(1, 1, 1, 1, ASTG(t + 3, 0); FEN(), (void)0);
    PH(1, 0, 1, 0, (void)0, VMW(4); BDEQ(t + 3, 1, bq1.y, bq1.w); LGK0());
  }
  {
    const int t = KT - 2;   // epilogue B: final tiles, drain
    PH(0, 0, 0, 1, ASTG(t + 1, 2); FEN(), (void)0);
    PH(0, 1, 0, 0, (void)0, VMW(4));
    PH(0, 1, 1, 1, (void)0, (void)0);
    PH(0, 0, 1, 0, (void)0, VMW(2));
    PH(1, 0, 0, 1, (void)0, VMW(0));
    PH(1, 1, 0, 0, (void)0, (void)0);
    PH(1, 1, 1, 1, (void)0, (void)0);
    PH(1, 0, 1, 0, (void)0, (void)0);
  }

  // Epilogue. C/D layout: col = lane&15, row = quad*4 + reg (m89/m91 verified).
  // Weights were dequantized UNSCALED (n-8): apply per-column scale here.
  const int crow0 = m0 + wm * 128 + quad * 4;
  const int ccol0 = n0 + wn * 64 + l16;
#pragma unroll
  for (int mf = 0; mf < 8; ++mf) {
#pragma unroll
    for (int rr = 0; rr < 4; ++rr) {
      const size_t row = (size_t)(crow0 + mf * 16 + rr);
#pragma unroll
      for (int nf = 0; nf < 4; ++nf) {
        float v = acc[mf][nf][rr] * scl[nf];
        const size_t idx = row * N + (size_t)(ccol0 + nf * 16);
        if constexpr (GELU) {
          Cb[idx] = f32_f16(gelu_tanh(v));
        } else {
          Cf[idx] = v;
        }
      }
    }
  }
}

#undef PH
#undef BDEQ
#undef BLOAD
#undef ASTG
#undef VMW
#undef LGK0
#undef FEN

// ---------------- Fallback: fused dequant GEMM (ws too small), f16 path -----
template <int K, int N, bool GELU>
__global__ void __launch_bounds__(256)
gemm_dq(const u16* __restrict__ A, const int* __restrict__ Bp,
        const float* __restrict__ Bsc, u16* __restrict__ Cb, float* __restrict__ Cf) {
  __shared__ __align__(16) u16 As[128 * 32];
  __shared__ __align__(16) u16 Bs[128 * 32];

  const int tid  = threadIdx.x;
  const int lane = tid & 63;
  const int wave = tid >> 6;
  const int quad = lane >> 4;
  const int l16  = lane & 15;
  const int wm = wave >> 1, wn = wave & 1;

  const int n0 = blockIdx.x * 128;
  const int m0 = blockIdx.y * 128;

  const int brow  = tid >> 1;
  const int bhalf = tid & 1;
  const float s   = Bsc[n0 + brow];
  const float m8s = -8.0f * s;
  const int4* bp  = (const int4*)(Bp + (size_t)(n0 + brow) * (K / 2)) + bhalf * 2;
  u16* blds = Bs + (brow >> 4) * 512 + (2 * bhalf) * 128 + (brow & 15) * 8;

  const u16* ag = A + (size_t)(m0 + l16) * K + (size_t)quad * 8;
  u16* alds0 = As + (wave * 2 + 0) * 512;
  u16* alds1 = As + (wave * 2 + 1) * 512;

  floatx4 acc[4][4];
#pragma unroll
  for (int i = 0; i < 4; ++i)
#pragma unroll
    for (int j = 0; j < 4; ++j)
      acc[i][j] = (floatx4){0.f, 0.f, 0.f, 0.f};

  const int KT = K / 32;
  for (int kt = 0; kt < KT; ++kt) {
    int4 w0 = bp[(size_t)kt * 4 + 0];
    int4 w1 = bp[(size_t)kt * 4 + 1];
    __syncthreads();
    gl_lds16(ag + (size_t)(wave * 2 + 0) * 16 * K + kt * 32, alds0);
    gl_lds16(ag + (size_t)(wave * 2 + 1) * 16 * K + kt * 32, alds1);
    int wv[8] = {w0.x, w0.y, w0.z, w0.w, w1.x, w1.y, w1.z, w1.w};
    union { u16 e[16]; uint4 q[2]; } u;
#pragma unroll
    for (int j = 0; j < 8; ++j) {
      int v = wv[j];
      u.e[2 * j]     = f32_f16(fmaf((float)(v >> 4), s, m8s));
      u.e[2 * j + 1] = f32_f16(fmaf((float)(v & 15), s, m8s));
    }
    *(uint4*)(blds)       = u.q[0];
    *(uint4*)(blds + 128) = u.q[1];
    __syncthreads();

    f16x8 af[4], bf[4];
#pragma unroll
    for (int im = 0; im < 4; ++im)
      af[im] = *(const f16x8*)(As + (wm * 4 + im) * 512 + quad * 128 + l16 * 8);
#pragma unroll
    for (int in = 0; in < 4; ++in)
      bf[in] = *(const f16x8*)(Bs + (wn * 4 + in) * 512 + quad * 128 + l16 * 8);
#pragma unroll
    for (int im = 0; im < 4; ++im)
#pragma unroll
      for (int in = 0; in < 4; ++in)
        acc[im][in] = __builtin_amdgcn_mfma_f32_16x16x32_f16(af[im], bf[in], acc[im][in], 0, 0, 0);
  }

#pragma unroll
  for (int im = 0; im < 4; ++im) {
#pragma unroll
    for (int r = 0; r < 4; ++r) {
      const int row = m0 + wm * 64 + im * 16 + quad * 4 + r;
#pragma unroll
      for (int in = 0; in < 4; ++in) {
        const int col = n0 + wn * 64 + in * 16 + l16;
        float v = acc[im][in][r];
        if constexpr (GELU) {
          Cb[(size_t)row * N + col] = f32_f16(gelu_tanh(v));
        } else {
          Cf[(size_t)row * N + col] = v;
        }
      }
    }
  }
}

extern "C" void kernel_launch(void* const* d_in, const int* in_sizes, int n_in,
                              void* d_out, int out_size, void* d_ws, size_t ws_size,
                              hipStream_t stream) {
  const float* x   = (const float*)d_in[0];
  const int*   f1p = (const int*)d_in[1];
  const float* f1s = (const float*)d_in[2];
  const int*   f2p = (const int*)d_in[3];
  const float* f2s = (const float*)d_in[4];
  float* out = (float*)d_out;

  const size_t xb_bytes  = (size_t)NTOK * D_MODEL * 2;            // 32 MiB
  const size_t h_bytes   = (size_t)NTOK * HIDDEN * 2;             // 128 MiB
  const size_t nib_bytes = (size_t)HIDDEN * D_MODEL / 2;          // 32 MiB each
  const size_t base      = xb_bytes + h_bytes;
  if (ws_size < base) return;

  u16* xb = (u16*)d_ws;
  u16* h  = xb + (size_t)NTOK * D_MODEL;

  cvt_f32_f16<<<(NTOK * D_MODEL) / 1024, 256, 0, stream>>>((const float4*)x, (ushort4*)xb);

  if (ws_size < base + 2 * nib_bytes) {
    // Fallback: fused dequant path (needs no extra ws)
    gemm_dq<D_MODEL, HIDDEN, true>
        <<<dim3(HIDDEN / 128, NTOK / 128), 256, 0, stream>>>(xb, f1p, f1s, h, nullptr);
    gemm_dq<HIDDEN, D_MODEL, false>
        <<<dim3(D_MODEL / 128, NTOK / 128), 256, 0, stream>>>(h, f2p, f2s, nullptr, out);
    return;
  }

  u32* nib1 = (u32*)(h + (size_t)NTOK * HIDDEN);                  // 32 MiB
  u32* nib2 = nib1 + nib_bytes / 4;                               // 32 MiB

  // Repack int32-per-byte packed weights to true nibble buffers.
  const int nblk = (int)((size_t)HIDDEN * (D_MODEL / 2) / 16 / 256);  // 8192
  repack_nib<<<nblk, 256, 0, stream>>>((const int4*)f1p, (uint4*)nib1);
  repack_nib<<<nblk, 256, 0, stream>>>((const int4*)f2p, (uint4*)nib2);

  // GEMM1: h = gelu(x @ W1^T)
  gemm_nt8<D_MODEL, HIDDEN, true>
      <<<dim3(HIDDEN / 256, NTOK / 256), 512, 0, stream>>>(xb, nib1, f1s, h, nullptr);
  // GEMM2: out = h @ W2^T
  gemm_nt8<HIDDEN, D_MODEL, false>
      <<<dim3(D_MODEL / 256, NTOK / 256), 512, 0, stream>>>(h, nib2, f2s, nullptr, out);
}